// Round 8
// baseline (552.492 us; speedup 1.0000x reference)
//
#include <hip/hip_runtime.h>
#include <hip/hip_bf16.h>
#include <cstdint>

// CrossAttention on MI355X — round 8 (2nd resubmit of round-6 delta; broker
// timeouts). vs round 5 (377us; attn 141us latency-bound, MfmaUtil 9.7%):
//  * attn: K-tile register double-buffer prefetch (K[t+1] issued after
//    QK^T[t], consumed a full tile later) -> K L2 latency off critical path.
//    launch_bounds(256,4) to keep VGPR<=128 (4 waves/SIMD).
//  * GEMMs: bijective XCD-chunk swizzle (T1) so same-A-panel blocks share an
//    XCD L2 -> A re-fetch ~/4.
#define NB   8
#define NIMG 4096
#define NTXT 512
#define DIMG 512
#define DTXT 768
#define NH   8
#define HD   64
#define SCALE 0.102062072615966f

typedef __attribute__((ext_vector_type(8))) short          s16x8;
typedef __attribute__((ext_vector_type(4))) unsigned short u16x4;
typedef __attribute__((ext_vector_type(4))) float          f32x4;
typedef unsigned short u16;
typedef unsigned int   u32;

union U8 { s16x8 v; u16 u[8]; };

__device__ __forceinline__ u16 f2bf(float f) {
  u32 u = __float_as_uint(f);
  u += 0x7fffu + ((u >> 16) & 1u);           // round-to-nearest-even
  return (u16)(u >> 16);
}
__device__ __forceinline__ s16x8 cvt8(float4 a, float4 b) {
  U8 t;
  t.u[0]=f2bf(a.x); t.u[1]=f2bf(a.y); t.u[2]=f2bf(a.z); t.u[3]=f2bf(a.w);
  t.u[4]=f2bf(b.x); t.u[5]=f2bf(b.y); t.u[6]=f2bf(b.z); t.u[7]=f2bf(b.w);
  return t.v;
}

// ---------------------------------------------------------------------------
// fp32 -> bf16 bulk convert
// ---------------------------------------------------------------------------
__global__ void convk(const float* __restrict__ in, u16* __restrict__ out, int n8) {
  int i = blockIdx.x * 256 + threadIdx.x;
  const int stride = gridDim.x * 256;
  for (; i < n8; i += stride) {
    float4 a = ((const float4*)in)[2 * i];
    float4 b = ((const float4*)in)[2 * i + 1];
    ((s16x8*)out)[i] = cvt8(a, b);
  }
}

// async global->LDS, 16B per lane; LDS dest = wave-uniform base + lane*16
__device__ __forceinline__ void gld16(const u16* g, u16* l) {
  __builtin_amdgcn_global_load_lds((const __attribute__((address_space(1))) u32*)g,
                                   (__attribute__((address_space(3))) u32*)l, 16, 0, 0);
}

// ---------------------------------------------------------------------------
// bf16 GEMM (m97 structure): C(M,N) = A(M,K) @ W(N,K)^T
// grid launched as dim3(4, M/128); XCD-chunk swizzled (nwg % 8 == 0).
// EPI 0: bf16 head-split (B,H,NPER,64);  EPI 2: fp32 + bias
// ---------------------------------------------------------------------------
template<int EPI, int NPER>
__global__ __launch_bounds__(256, 2)
void gemm_bf(const u16* __restrict__ A, const u16* __restrict__ W,
             const float* __restrict__ bias, void* __restrict__ Cp,
             const int N, const int K) {
  __shared__ u16 As[128 * 64];
  __shared__ u16 Bs[128 * 64];
  const int tid = threadIdx.x, lane = tid & 63, w = tid >> 6;
  const int l15 = lane & 15, l4 = lane >> 4;
  const int wm = (w >> 1) * 64, wn = (w & 1) * 64;
  // XCD swizzle: orig%8 = XCD; give each XCD a contiguous run of row-panels.
  const int nwg  = gridDim.x * gridDim.y;                  // multiple of 8
  const int orig = blockIdx.y * gridDim.x + blockIdx.x;
  const int nid  = (orig & 7) * (nwg >> 3) + (orig >> 3);
  const int m0 = (nid >> 2) * 128, n0 = (nid & 3) * 128;   // gridDim.x == 4
  const int srow = lane >> 3, schk = lane & 7;

  f32x4 acc[4][4] = {};

  for (int k0 = 0; k0 < K; k0 += 64) {
    __syncthreads();
#pragma unroll
    for (int i = 0; i < 4; ++i) {
      const int rg  = (w * 4 + i) * 8;
      const int row = rg + srow;
      const int sc  = schk ^ (row & 7);           // pre-swizzled source chunk
      gld16(A + (size_t)(m0 + row) * K + k0 + sc * 8, &As[rg * 64]);
      gld16(W + (size_t)(n0 + row) * K + k0 + sc * 8, &Bs[rg * 64]);
    }
    __syncthreads();
#pragma unroll
    for (int ks = 0; ks < 2; ++ks) {
      s16x8 af[4], bw[4];
#pragma unroll
      for (int mf = 0; mf < 4; ++mf) {
        const int row = wm + mf * 16 + l15;
        af[mf] = *(const s16x8*)&As[row * 64 + (((ks * 4 + l4) ^ (row & 7)) << 3)];
      }
#pragma unroll
      for (int nf = 0; nf < 4; ++nf) {
        const int row = wn + nf * 16 + l15;
        bw[nf] = *(const s16x8*)&Bs[row * 64 + (((ks * 4 + l4) ^ (row & 7)) << 3)];
      }
#pragma unroll
      for (int mf = 0; mf < 4; ++mf)
#pragma unroll
        for (int nf = 0; nf < 4; ++nf)
          acc[mf][nf] = __builtin_amdgcn_mfma_f32_16x16x32_bf16(af[mf], bw[nf], acc[mf][nf], 0, 0, 0);
    }
  }

#pragma unroll
  for (int mf = 0; mf < 4; ++mf)
#pragma unroll
    for (int nf = 0; nf < 4; ++nf)
#pragma unroll
      for (int r = 0; r < 4; ++r) {
        const int grow = m0 + wm + mf * 16 + l4 * 4 + r;
        const int gcol = n0 + wn + nf * 16 + l15;
        const float v = acc[mf][nf][r];
        if constexpr (EPI == 2) {
          ((float*)Cp)[(size_t)grow * N + gcol] = v + bias[gcol];
        } else {
          const int bb = grow / NPER, nr = grow % NPER;
          const int hh = gcol >> 6, dd = gcol & 63;
          ((u16*)Cp)[((size_t)(bb * NH + hh) * NPER + nr) * HD + dd] = f2bf(v);
        }
      }
}

// ---------------------------------------------------------------------------
// K+V projection fused (fp32 inputs, cvt-staging). XCD-chunk swizzled.
// bx 0-3 -> K columns (Kbf layout), 4-7 -> V columns (V^T layout).
// ---------------------------------------------------------------------------
__global__ __launch_bounds__(256, 2)
void gemm_kv(const float* __restrict__ txt, const float* __restrict__ Wk,
             const float* __restrict__ Wv, u16* __restrict__ Kbf,
             u16* __restrict__ Vtw) {
  constexpr int K = DTXT;
  __shared__ u16 As[128 * 64];
  __shared__ u16 Bs[128 * 64];
  const int tid = threadIdx.x, lane = tid & 63, w = tid >> 6;
  const int l15 = lane & 15, l4 = lane >> 4;
  const int wm = (w >> 1) * 64, wn = (w & 1) * 64;
  const int orig = blockIdx.y * 8 + blockIdx.x;            // nwg = 256
  const int nid  = (orig & 7) * 32 + (orig >> 3);
  const int bx = nid & 7, by = nid >> 3;
  const float* W = (bx < 4) ? Wk : Wv;
  const int n0 = (bx & 3) * 128;
  const int m0 = by * 128;

  f32x4 acc[4][4] = {};

  for (int k0 = 0; k0 < K; k0 += 64) {
    __syncthreads();
#pragma unroll
    for (int p = 0; p < 4; ++p) {
      const int q = tid + p * 256;
      const int row = q >> 3, c = q & 7;
      const int dst = row * 64 + ((c ^ (row & 7)) << 3);
      const float* sa = txt + (size_t)(m0 + row) * K + k0 + c * 8;
      *(s16x8*)&As[dst] = cvt8(*(const float4*)sa, *(const float4*)(sa + 4));
      const float* sw = W + (size_t)(n0 + row) * K + k0 + c * 8;
      *(s16x8*)&Bs[dst] = cvt8(*(const float4*)sw, *(const float4*)(sw + 4));
    }
    __syncthreads();
#pragma unroll
    for (int ks = 0; ks < 2; ++ks) {
      s16x8 af[4], bw[4];
#pragma unroll
      for (int mf = 0; mf < 4; ++mf) {
        const int row = wm + mf * 16 + l15;
        af[mf] = *(const s16x8*)&As[row * 64 + (((ks * 4 + l4) ^ (row & 7)) << 3)];
      }
#pragma unroll
      for (int nf = 0; nf < 4; ++nf) {
        const int row = wn + nf * 16 + l15;
        bw[nf] = *(const s16x8*)&Bs[row * 64 + (((ks * 4 + l4) ^ (row & 7)) << 3)];
      }
#pragma unroll
      for (int mf = 0; mf < 4; ++mf)
#pragma unroll
        for (int nf = 0; nf < 4; ++nf)
          acc[mf][nf] = __builtin_amdgcn_mfma_f32_16x16x32_bf16(af[mf], bw[nf], acc[mf][nf], 0, 0, 0);
    }
  }

#pragma unroll
  for (int mf = 0; mf < 4; ++mf)
#pragma unroll
    for (int nf = 0; nf < 4; ++nf)
#pragma unroll
      for (int r = 0; r < 4; ++r) {
        const int grow = m0 + wm + mf * 16 + l4 * 4 + r;   // 0..4095
        const int gcol = n0 + wn + nf * 16 + l15;          // 0..511
        const int bb = grow >> 9, nr = grow & 511;
        const int hh = gcol >> 6, dd = gcol & 63;
        const u16 v = f2bf(acc[mf][nf][r]);
        if (bx < 4)
          Kbf[((size_t)(bb * NH + hh) * NTXT + nr) * HD + dd] = v;
        else
          Vtw[((size_t)(bb * NH + hh) * HD + dd) * NTXT + nr] = v;
      }
}

// ---------------------------------------------------------------------------
// Flash attention, swapped QK^T (S^T = K*Q^T), K-tile register prefetch.
// Block = 128 q-rows of one (b,h), 4 waves. Softmax state lives on lane
// q=l15; O-frag rows are q=l4*4+r -> alpha / 1/lst shuffled from
// lane (lane&48)|(l4*4+r) (r5 fix).
// ---------------------------------------------------------------------------
__global__ __launch_bounds__(256, 4)
void attn_k(const u16* __restrict__ Qbf,   // (B,H,4096,64)
            const u16* __restrict__ Kbf,   // (B,H,512,64)
            const u16* __restrict__ Vt,    // (B,H,64,512)
            const int* __restrict__ msk,   // (B,512)
            u16* __restrict__ Abf) {       // (B,4096,512)
  __shared__ u16 Plds[4][32 * 64];
  const int blk = blockIdx.x;
  const int qt = blk & 31, bh = blk >> 5;
  const int b = bh >> 3, h = bh & 7;
  const int tid = threadIdx.x, lane = tid & 63, w = tid >> 6;
  const int l15 = lane & 15, l4 = lane >> 4;
  const int sbase = lane & 48;

  const u16* Qb = Qbf + (size_t)bh * NIMG * HD;
  const u16* Kb = Kbf + (size_t)bh * NTXT * HD;
  const u16* Vb = Vt  + (size_t)bh * HD * NTXT;
  const int* mb = msk + b * NTXT;
  const int qrow0 = qt * 128 + w * 32;

  // Q as B-operand frags
  s16x8 aq[2][2];
#pragma unroll
  for (int nfq = 0; nfq < 2; ++nfq)
#pragma unroll
    for (int ks = 0; ks < 2; ++ks)
      aq[nfq][ks] = *(const s16x8*)(Qb + (size_t)(qrow0 + nfq * 16 + l15) * HD + ks * 32 + l4 * 8);

  f32x4 o[2][4] = {};
  float mst[2] = {-1e30f, -1e30f}, lst[2] = {0.f, 0.f};

  // K-tile double buffer: prologue loads tile 0 into bkA.
  s16x8 bkA[4][2], bkB[4][2];
#pragma unroll
  for (int mfk = 0; mfk < 4; ++mfk)
#pragma unroll
    for (int ks = 0; ks < 2; ++ks)
      bkA[mfk][ks] = *(const s16x8*)(Kb + (size_t)(mfk * 16 + l15) * HD + ks * 32 + l4 * 8);

  auto tile = [&](int j0, s16x8 (&bkc)[4][2], s16x8 (&bkn)[4][2], int pj0, bool pf) {
    // S^T[kv][q] from the CURRENT (already-loaded) K buffer
    f32x4 st[4][2] = {};
#pragma unroll
    for (int ks = 0; ks < 2; ++ks)
#pragma unroll
      for (int mfk = 0; mfk < 4; ++mfk)
#pragma unroll
        for (int nfq = 0; nfq < 2; ++nfq)
          st[mfk][nfq] = __builtin_amdgcn_mfma_f32_16x16x32_bf16(bkc[mfk][ks], aq[nfq][ks], st[mfk][nfq], 0, 0, 0);

    // PREFETCH next K tile: consumed a full tile later (softmax+PV hide it)
    if (pf) {
#pragma unroll
      for (int mfk = 0; mfk < 4; ++mfk)
#pragma unroll
        for (int ks = 0; ks < 2; ++ks)
          bkn[mfk][ks] = *(const s16x8*)(Kb + (size_t)(pj0 + mfk * 16 + l15) * HD + ks * 32 + l4 * 8);
    }

    // V frags for this tile: issued early, consumed after softmax
    s16x8 bv[4][2];
#pragma unroll
    for (int hf = 0; hf < 4; ++hf)
#pragma unroll
      for (int ks = 0; ks < 2; ++ks)
        bv[hf][ks] = *(const s16x8*)(Vb + (size_t)(hf * 16 + l15) * NTXT + j0 + ks * 32 + l4 * 8);

    // mask addend: kv = mfk*16 + l4*4 + r
    float madd[4][4];
#pragma unroll
    for (int mfk = 0; mfk < 4; ++mfk) {
      const int4 mm = *(const int4*)(mb + j0 + mfk * 16 + l4 * 4);
      madd[mfk][0] = mm.x ? 0.f : -1e30f;
      madd[mfk][1] = mm.y ? 0.f : -1e30f;
      madd[mfk][2] = mm.z ? 0.f : -1e30f;
      madd[mfk][3] = mm.w ? 0.f : -1e30f;
    }

#pragma unroll
    for (int nfq = 0; nfq < 2; ++nfq) {
      float nm = -1e30f;
#pragma unroll
      for (int mfk = 0; mfk < 4; ++mfk)
#pragma unroll
        for (int r = 0; r < 4; ++r) {
          const float sv = st[mfk][nfq][r] * SCALE + madd[mfk][r];
          st[mfk][nfq][r] = sv;
          nm = fmaxf(nm, sv);
        }
      nm = fmaxf(nm, __shfl_xor(nm, 16));
      nm = fmaxf(nm, __shfl_xor(nm, 32));
      const float mn = fmaxf(mst[nfq], nm);
      const float alpha = __expf(mst[nfq] - mn);
      mst[nfq] = mn;
      float ps = 0.f;
#pragma unroll
      for (int mfk = 0; mfk < 4; ++mfk)
#pragma unroll
        for (int r = 0; r < 4; ++r) {
          const float p = __expf(st[mfk][nfq][r] - mn);
          st[mfk][nfq][r] = p;
          ps += p;
        }
      ps += __shfl_xor(ps, 16);
      ps += __shfl_xor(ps, 32);
      lst[nfq] = lst[nfq] * alpha + ps;

      // o rows are q = nfq*16 + l4*4 + r: fetch each row's alpha (r5 fix)
      float ar[4];
#pragma unroll
      for (int r = 0; r < 4; ++r) ar[r] = __shfl(alpha, sbase + l4 * 4 + r);
#pragma unroll
      for (int hf = 0; hf < 4; ++hf)
#pragma unroll
        for (int r = 0; r < 4; ++r) o[nfq][hf][r] *= ar[r];

      // P[q][kv] -> LDS, b64 writes, 8B-chunk XOR swizzle
      const int q = nfq * 16 + l15;
      const int E = (q & 7) << 1;
#pragma unroll
      for (int mfk = 0; mfk < 4; ++mfk) {
        u16x4 pk;
        pk[0] = f2bf(st[mfk][nfq][0]); pk[1] = f2bf(st[mfk][nfq][1]);
        pk[2] = f2bf(st[mfk][nfq][2]); pk[3] = f2bf(st[mfk][nfq][3]);
        const int c8 = mfk * 4 + l4;
        *(u16x4*)((char*)&Plds[w][0] + q * 128 + (((c8) ^ E) << 3)) = pk;
      }
    }
    asm volatile("" ::: "memory");

    // PV: O[q][d] += P[q][kv] * V[kv][d]
#pragma unroll
    for (int mfq = 0; mfq < 2; ++mfq) {
      const int q = mfq * 16 + l15;
      const int E = (q & 7) << 1;
      s16x8 pa[2];
#pragma unroll
      for (int ks = 0; ks < 2; ++ks)
        pa[ks] = *(const s16x8*)((const char*)&Plds[w][0] + q * 128 + (((ks * 8 + l4 * 2) ^ E) << 3));
#pragma unroll
      for (int hf = 0; hf < 4; ++hf)
#pragma unroll
        for (int ks = 0; ks < 2; ++ks)
          o[mfq][hf] = __builtin_amdgcn_mfma_f32_16x16x32_bf16(pa[ks], bv[hf][ks], o[mfq][hf], 0, 0, 0);
    }
  };

  for (int t = 0; t < 8; t += 2) {
    tile(t * 64,       bkA, bkB, (t + 1) * 64, true);
    tile((t + 1) * 64, bkB, bkA, (t + 2) * 64, t < 6);
  }

  // epilogue — row-state shuffle for 1/lst
#pragma unroll
  for (int nfq = 0; nfq < 2; ++nfq) {
    const float rl = 1.f / lst[nfq];
    float rr[4];
#pragma unroll
    for (int r = 0; r < 4; ++r) rr[r] = __shfl(rl, sbase + l4 * 4 + r);
#pragma unroll
    for (int hf = 0; hf < 4; ++hf)
#pragma unroll
      for (int r = 0; r < 4; ++r) {
        const int qrow = qrow0 + nfq * 16 + l4 * 4 + r;
        const int col = h * 64 + hf * 16 + l15;
        Abf[((size_t)b * NIMG + qrow) * DIMG + col] = f2bf(o[nfq][hf][r] * rr[r]);
      }
  }
}

// ---------------------------------------------------------------------------
extern "C" void kernel_launch(void* const* d_in, const int* in_sizes, int n_in,
                              void* d_out, int out_size, void* d_ws, size_t ws_size,
                              hipStream_t stream) {
  const float* img  = (const float*)d_in[0];
  const float* txt  = (const float*)d_in[1];
  const int*   mask = (const int*)d_in[2];
  const float* Wq   = (const float*)d_in[3];
  const float* Wk   = (const float*)d_in[4];
  const float* Wv   = (const float*)d_in[5];
  const float* Wo   = (const float*)d_in[6];
  const float* bo   = (const float*)d_in[7];
  float* out = (float*)d_out;

  char* ws = (char*)d_ws;
  u16* imgBf = (u16*)ws;                        // 33.55 MB; reused as Abf after Q-proj
  u16* Qbf   = (u16*)(ws + 33554432);           // 33.55 MB
  u16* Kbf   = (u16*)(ws + 67108864);           //  4.19 MB
  u16* Vtw   = (u16*)(ws + 71303168);           //  4.19 MB
  u16* WqBf  = (u16*)(ws + 75497472);           //  0.52 MB
  u16* WoBf  = (u16*)(ws + 76021760);           //  0.52 MB  (total 76.5 MB)

  convk<<<2048, 256, 0, stream>>>(img, imgBf, NB * NIMG * DIMG / 8);
  convk<<<128,  256, 0, stream>>>(Wq, WqBf, DIMG * DIMG / 8);
  convk<<<128,  256, 0, stream>>>(Wo, WoBf, DIMG * DIMG / 8);

  // Q = img @ Wq^T  (32768 x 512 x 512), head-split bf16
  gemm_bf<0, NIMG><<<dim3(4, 256), 256, 0, stream>>>(imgBf, WqBf, nullptr, Qbf, DIMG, DIMG);
  // K, V^T = txt @ {Wk,Wv}^T  (4096 x 512 x 768)
  gemm_kv<<<dim3(8, 32), 256, 0, stream>>>(txt, Wk, Wv, Kbf, Vtw);
  // attention -> Abf (overwrites imgBf; img dead after Q-proj)
  attn_k<<<dim3(NB * NH * (NIMG / 128)), 256, 0, stream>>>(Qbf, Kbf, Vtw, mask, imgBf);
  // out = attended @ Wo^T + bo  (32768 x 512 x 512), fp32
  gemm_bf<2, 1><<<dim3(4, 256), 256, 0, stream>>>(imgBf, WoBf, bo, out, DIMG, DIMG);
}

// Round 9
// 317.696 us; speedup vs baseline: 1.7391x; 1.7391x over previous
//
#include <hip/hip_runtime.h>
#include <hip/hip_bf16.h>
#include <cstdint>

// CrossAttention on MI355X — round 9.
// r8 post-mortem: register K-prefetch + launch_bounds(256,4) caused VGPR=64
// + 1.4 GB scratch spill traffic (attn 141->335us). REVERTED.
// r9: K/V prefetch through LDS via global_load_lds (async, zero VGPR cost),
// double-buffered; one sync per tile drains the async queue. Staging uses the
// gemm_bf-proven pre-swizzled-source + swizzled ds_read_b128 pattern.
// GEMMs keep the bijective XCD-chunk swizzle (r8: non-attn 217us vs 236 r5).
#define NB   8
#define NIMG 4096
#define NTXT 512
#define DIMG 512
#define DTXT 768
#define NH   8
#define HD   64
#define SCALE 0.102062072615966f

typedef __attribute__((ext_vector_type(8))) short          s16x8;
typedef __attribute__((ext_vector_type(4))) unsigned short u16x4;
typedef __attribute__((ext_vector_type(4))) float          f32x4;
typedef unsigned short u16;
typedef unsigned int   u32;

union U8 { s16x8 v; u16 u[8]; };

__device__ __forceinline__ u16 f2bf(float f) {
  u32 u = __float_as_uint(f);
  u += 0x7fffu + ((u >> 16) & 1u);           // round-to-nearest-even
  return (u16)(u >> 16);
}
__device__ __forceinline__ s16x8 cvt8(float4 a, float4 b) {
  U8 t;
  t.u[0]=f2bf(a.x); t.u[1]=f2bf(a.y); t.u[2]=f2bf(a.z); t.u[3]=f2bf(a.w);
  t.u[4]=f2bf(b.x); t.u[5]=f2bf(b.y); t.u[6]=f2bf(b.z); t.u[7]=f2bf(b.w);
  return t.v;
}

// ---------------------------------------------------------------------------
// fp32 -> bf16 bulk convert
// ---------------------------------------------------------------------------
__global__ void convk(const float* __restrict__ in, u16* __restrict__ out, int n8) {
  int i = blockIdx.x * 256 + threadIdx.x;
  const int stride = gridDim.x * 256;
  for (; i < n8; i += stride) {
    float4 a = ((const float4*)in)[2 * i];
    float4 b = ((const float4*)in)[2 * i + 1];
    ((s16x8*)out)[i] = cvt8(a, b);
  }
}

// async global->LDS, 16B per lane; LDS dest = wave-uniform base + lane*16
__device__ __forceinline__ void gld16(const u16* g, u16* l) {
  __builtin_amdgcn_global_load_lds((const __attribute__((address_space(1))) u32*)g,
                                   (__attribute__((address_space(3))) u32*)l, 16, 0, 0);
}

// ---------------------------------------------------------------------------
// bf16 GEMM (m97 structure): C(M,N) = A(M,K) @ W(N,K)^T
// grid launched as dim3(4, M/128); XCD-chunk swizzled (nwg % 8 == 0).
// EPI 0: bf16 head-split (B,H,NPER,64);  EPI 2: fp32 + bias
// ---------------------------------------------------------------------------
template<int EPI, int NPER>
__global__ __launch_bounds__(256, 2)
void gemm_bf(const u16* __restrict__ A, const u16* __restrict__ W,
             const float* __restrict__ bias, void* __restrict__ Cp,
             const int N, const int K) {
  __shared__ u16 As[128 * 64];
  __shared__ u16 Bs[128 * 64];
  const int tid = threadIdx.x, lane = tid & 63, w = tid >> 6;
  const int l15 = lane & 15, l4 = lane >> 4;
  const int wm = (w >> 1) * 64, wn = (w & 1) * 64;
  // XCD swizzle: orig%8 = XCD; give each XCD a contiguous run of row-panels.
  const int nwg  = gridDim.x * gridDim.y;                  // multiple of 8
  const int orig = blockIdx.y * gridDim.x + blockIdx.x;
  const int nid  = (orig & 7) * (nwg >> 3) + (orig >> 3);
  const int m0 = (nid >> 2) * 128, n0 = (nid & 3) * 128;   // gridDim.x == 4
  const int srow = lane >> 3, schk = lane & 7;

  f32x4 acc[4][4] = {};

  for (int k0 = 0; k0 < K; k0 += 64) {
    __syncthreads();
#pragma unroll
    for (int i = 0; i < 4; ++i) {
      const int rg  = (w * 4 + i) * 8;
      const int row = rg + srow;
      const int sc  = schk ^ (row & 7);           // pre-swizzled source chunk
      gld16(A + (size_t)(m0 + row) * K + k0 + sc * 8, &As[rg * 64]);
      gld16(W + (size_t)(n0 + row) * K + k0 + sc * 8, &Bs[rg * 64]);
    }
    __syncthreads();
#pragma unroll
    for (int ks = 0; ks < 2; ++ks) {
      s16x8 af[4], bw[4];
#pragma unroll
      for (int mf = 0; mf < 4; ++mf) {
        const int row = wm + mf * 16 + l15;
        af[mf] = *(const s16x8*)&As[row * 64 + (((ks * 4 + l4) ^ (row & 7)) << 3)];
      }
#pragma unroll
      for (int nf = 0; nf < 4; ++nf) {
        const int row = wn + nf * 16 + l15;
        bw[nf] = *(const s16x8*)&Bs[row * 64 + (((ks * 4 + l4) ^ (row & 7)) << 3)];
      }
#pragma unroll
      for (int mf = 0; mf < 4; ++mf)
#pragma unroll
        for (int nf = 0; nf < 4; ++nf)
          acc[mf][nf] = __builtin_amdgcn_mfma_f32_16x16x32_bf16(af[mf], bw[nf], acc[mf][nf], 0, 0, 0);
    }
  }

#pragma unroll
  for (int mf = 0; mf < 4; ++mf)
#pragma unroll
    for (int nf = 0; nf < 4; ++nf)
#pragma unroll
      for (int r = 0; r < 4; ++r) {
        const int grow = m0 + wm + mf * 16 + l4 * 4 + r;
        const int gcol = n0 + wn + nf * 16 + l15;
        const float v = acc[mf][nf][r];
        if constexpr (EPI == 2) {
          ((float*)Cp)[(size_t)grow * N + gcol] = v + bias[gcol];
        } else {
          const int bb = grow / NPER, nr = grow % NPER;
          const int hh = gcol >> 6, dd = gcol & 63;
          ((u16*)Cp)[((size_t)(bb * NH + hh) * NPER + nr) * HD + dd] = f2bf(v);
        }
      }
}

// ---------------------------------------------------------------------------
// K+V projection fused (fp32 inputs, cvt-staging). XCD-chunk swizzled.
// bx 0-3 -> K columns (Kbf layout), 4-7 -> V columns (V^T layout).
// ---------------------------------------------------------------------------
__global__ __launch_bounds__(256, 2)
void gemm_kv(const float* __restrict__ txt, const float* __restrict__ Wk,
             const float* __restrict__ Wv, u16* __restrict__ Kbf,
             u16* __restrict__ Vtw) {
  constexpr int K = DTXT;
  __shared__ u16 As[128 * 64];
  __shared__ u16 Bs[128 * 64];
  const int tid = threadIdx.x, lane = tid & 63, w = tid >> 6;
  const int l15 = lane & 15, l4 = lane >> 4;
  const int wm = (w >> 1) * 64, wn = (w & 1) * 64;
  const int orig = blockIdx.y * 8 + blockIdx.x;            // nwg = 256
  const int nid  = (orig & 7) * 32 + (orig >> 3);
  const int bx = nid & 7, by = nid >> 3;
  const float* W = (bx < 4) ? Wk : Wv;
  const int n0 = (bx & 3) * 128;
  const int m0 = by * 128;

  f32x4 acc[4][4] = {};

  for (int k0 = 0; k0 < K; k0 += 64) {
    __syncthreads();
#pragma unroll
    for (int p = 0; p < 4; ++p) {
      const int q = tid + p * 256;
      const int row = q >> 3, c = q & 7;
      const int dst = row * 64 + ((c ^ (row & 7)) << 3);
      const float* sa = txt + (size_t)(m0 + row) * K + k0 + c * 8;
      *(s16x8*)&As[dst] = cvt8(*(const float4*)sa, *(const float4*)(sa + 4));
      const float* sw = W + (size_t)(n0 + row) * K + k0 + c * 8;
      *(s16x8*)&Bs[dst] = cvt8(*(const float4*)sw, *(const float4*)(sw + 4));
    }
    __syncthreads();
#pragma unroll
    for (int ks = 0; ks < 2; ++ks) {
      s16x8 af[4], bw[4];
#pragma unroll
      for (int mf = 0; mf < 4; ++mf) {
        const int row = wm + mf * 16 + l15;
        af[mf] = *(const s16x8*)&As[row * 64 + (((ks * 4 + l4) ^ (row & 7)) << 3)];
      }
#pragma unroll
      for (int nf = 0; nf < 4; ++nf) {
        const int row = wn + nf * 16 + l15;
        bw[nf] = *(const s16x8*)&Bs[row * 64 + (((ks * 4 + l4) ^ (row & 7)) << 3)];
      }
#pragma unroll
      for (int mf = 0; mf < 4; ++mf)
#pragma unroll
        for (int nf = 0; nf < 4; ++nf)
          acc[mf][nf] = __builtin_amdgcn_mfma_f32_16x16x32_bf16(af[mf], bw[nf], acc[mf][nf], 0, 0, 0);
    }
  }

#pragma unroll
  for (int mf = 0; mf < 4; ++mf)
#pragma unroll
    for (int nf = 0; nf < 4; ++nf)
#pragma unroll
      for (int r = 0; r < 4; ++r) {
        const int grow = m0 + wm + mf * 16 + l4 * 4 + r;   // 0..4095
        const int gcol = n0 + wn + nf * 16 + l15;          // 0..511
        const int bb = grow >> 9, nr = grow & 511;
        const int hh = gcol >> 6, dd = gcol & 63;
        const u16 v = f2bf(acc[mf][nf][r]);
        if (bx < 4)
          Kbf[((size_t)(bb * NH + hh) * NTXT + nr) * HD + dd] = v;
        else
          Vtw[((size_t)(bb * NH + hh) * HD + dd) * NTXT + nr] = v;
      }
}

// ---------------------------------------------------------------------------
// Flash attention, swapped QK^T (S^T = K*Q^T), K/V double-buffered in LDS
// via global_load_lds (async; zero VGPR cost — r8's register prefetch
// spilled). Per tile: sync (drain) -> K frags -> QK^T -> issue stage(t+1)
// -> softmax -> P->Plds -> V frags -> PV. Softmax row-state shuffled to
// O-frag rows (r5 fix).
// ---------------------------------------------------------------------------
__global__ __launch_bounds__(256, 2)
void attn_k(const u16* __restrict__ Qbf,   // (B,H,4096,64)
            const u16* __restrict__ Kbf,   // (B,H,512,64)
            const u16* __restrict__ Vt,    // (B,H,64,512)
            const int* __restrict__ msk,   // (B,512)
            u16* __restrict__ Abf) {       // (B,4096,512)
  __shared__ u16 Ks[2][64 * 64];
  __shared__ u16 Vs[2][64 * 64];
  __shared__ u16 Plds[4][32 * 64];
  const int blk = blockIdx.x;
  const int qt = blk & 31, bh = blk >> 5;
  const int b = bh >> 3, h = bh & 7;
  const int tid = threadIdx.x, lane = tid & 63, w = tid >> 6;
  const int l15 = lane & 15, l4 = lane >> 4;
  const int sbase = lane & 48;
  const int srow = lane >> 3, schk = lane & 7;

  const u16* Qb = Qbf + (size_t)bh * NIMG * HD;
  const u16* Kb = Kbf + (size_t)bh * NTXT * HD;
  const u16* Vb = Vt  + (size_t)bh * HD * NTXT;
  const int* mb = msk + b * NTXT;
  const int qrow0 = qt * 128 + w * 32;

  // Q as B-operand frags (persistent)
  s16x8 aq[2][2];
#pragma unroll
  for (int nfq = 0; nfq < 2; ++nfq)
#pragma unroll
    for (int ks = 0; ks < 2; ++ks)
      aq[nfq][ks] = *(const s16x8*)(Qb + (size_t)(qrow0 + nfq * 16 + l15) * HD + ks * 32 + l4 * 8);

  f32x4 o[2][4] = {};
  float mst[2] = {-1e30f, -1e30f}, lst[2] = {0.f, 0.f};

  // stage K-tile + V-tile tt into buffer bb (4 gld16/wave; linear LDS dest,
  // pre-swizzled global source — both-sides pattern, rule #21)
  auto stage = [&](int bb, int tt) {
    const int j0 = tt * 64;
#pragma unroll
    for (int i = 0; i < 2; ++i) {
      const int rg  = (w * 2 + i) * 8;        // 8-row group
      const int row = rg + srow;
      const int sc  = schk ^ (row & 7);
      gld16(Kb + (size_t)(j0 + row) * HD + sc * 8, &Ks[bb][rg * 64]);
      gld16(Vb + (size_t)row * NTXT + j0 + sc * 8, &Vs[bb][rg * 64]);
    }
  };

  stage(0, 0);
  int cur = 0;

  for (int t = 0; t < 8; ++t) {
    const int j0 = t * 64;
    __syncthreads();                           // drains vmcnt: buf[cur] ready

    // K frags from LDS: lane holds K[j0+mfk*16+l15][ks*32+l4*8 ..+7]
    s16x8 bk[4][2];
#pragma unroll
    for (int mfk = 0; mfk < 4; ++mfk)
#pragma unroll
      for (int ks = 0; ks < 2; ++ks) {
        const int row = mfk * 16 + l15;
        bk[mfk][ks] = *(const s16x8*)&Ks[cur][row * 64 + (((ks * 4 + l4) ^ (row & 7)) << 3)];
      }

    // S^T[kv][q]
    f32x4 st[4][2] = {};
#pragma unroll
    for (int ks = 0; ks < 2; ++ks)
#pragma unroll
      for (int mfk = 0; mfk < 4; ++mfk)
#pragma unroll
        for (int nfq = 0; nfq < 2; ++nfq)
          st[mfk][nfq] = __builtin_amdgcn_mfma_f32_16x16x32_bf16(bk[mfk][ks], aq[nfq][ks], st[mfk][nfq], 0, 0, 0);

    // issue next tile's async stage NOW — hidden under softmax + PV
    if (t < 7) stage(cur ^ 1, t + 1);

    // mask addend: kv = mfk*16 + l4*4 + r
    float madd[4][4];
#pragma unroll
    for (int mfk = 0; mfk < 4; ++mfk) {
      const int4 mm = *(const int4*)(mb + j0 + mfk * 16 + l4 * 4);
      madd[mfk][0] = mm.x ? 0.f : -1e30f;
      madd[mfk][1] = mm.y ? 0.f : -1e30f;
      madd[mfk][2] = mm.z ? 0.f : -1e30f;
      madd[mfk][3] = mm.w ? 0.f : -1e30f;
    }

#pragma unroll
    for (int nfq = 0; nfq < 2; ++nfq) {
      float nm = -1e30f;
#pragma unroll
      for (int mfk = 0; mfk < 4; ++mfk)
#pragma unroll
        for (int r = 0; r < 4; ++r) {
          const float sv = st[mfk][nfq][r] * SCALE + madd[mfk][r];
          st[mfk][nfq][r] = sv;
          nm = fmaxf(nm, sv);
        }
      nm = fmaxf(nm, __shfl_xor(nm, 16));
      nm = fmaxf(nm, __shfl_xor(nm, 32));
      const float mn = fmaxf(mst[nfq], nm);
      const float alpha = __expf(mst[nfq] - mn);
      mst[nfq] = mn;
      float ps = 0.f;
#pragma unroll
      for (int mfk = 0; mfk < 4; ++mfk)
#pragma unroll
        for (int r = 0; r < 4; ++r) {
          const float p = __expf(st[mfk][nfq][r] - mn);
          st[mfk][nfq][r] = p;
          ps += p;
        }
      ps += __shfl_xor(ps, 16);
      ps += __shfl_xor(ps, 32);
      lst[nfq] = lst[nfq] * alpha + ps;

      // o rows are q = nfq*16 + l4*4 + r: fetch each row's alpha (r5 fix)
      float ar[4];
#pragma unroll
      for (int r = 0; r < 4; ++r) ar[r] = __shfl(alpha, sbase + l4 * 4 + r);
#pragma unroll
      for (int hf = 0; hf < 4; ++hf)
#pragma unroll
        for (int r = 0; r < 4; ++r) o[nfq][hf][r] *= ar[r];

      // P[q][kv] -> LDS, b64 writes, 8B-chunk XOR swizzle
      const int q = nfq * 16 + l15;
      const int E = (q & 7) << 1;
#pragma unroll
      for (int mfk = 0; mfk < 4; ++mfk) {
        u16x4 pk;
        pk[0] = f2bf(st[mfk][nfq][0]); pk[1] = f2bf(st[mfk][nfq][1]);
        pk[2] = f2bf(st[mfk][nfq][2]); pk[3] = f2bf(st[mfk][nfq][3]);
        const int c8 = mfk * 4 + l4;
        *(u16x4*)((char*)&Plds[w][0] + q * 128 + (((c8) ^ E) << 3)) = pk;
      }
    }
    asm volatile("" ::: "memory");

    // V frags from LDS: lane holds V^T[hf*16+l15][j0+ks*32+l4*8 ..+7]
    s16x8 bv[4][2];
#pragma unroll
    for (int hf = 0; hf < 4; ++hf)
#pragma unroll
      for (int ks = 0; ks < 2; ++ks) {
        const int row = hf * 16 + l15;
        bv[hf][ks] = *(const s16x8*)&Vs[cur][row * 64 + (((ks * 4 + l4) ^ (row & 7)) << 3)];
      }

    // PV: O[q][d] += P[q][kv] * V[kv][d]
#pragma unroll
    for (int mfq = 0; mfq < 2; ++mfq) {
      const int q = mfq * 16 + l15;
      const int E = (q & 7) << 1;
      s16x8 pa[2];
#pragma unroll
      for (int ks = 0; ks < 2; ++ks)
        pa[ks] = *(const s16x8*)((const char*)&Plds[w][0] + q * 128 + (((ks * 8 + l4 * 2) ^ E) << 3));
#pragma unroll
      for (int hf = 0; hf < 4; ++hf)
#pragma unroll
        for (int ks = 0; ks < 2; ++ks)
          o[mfq][hf] = __builtin_amdgcn_mfma_f32_16x16x32_bf16(pa[ks], bv[hf][ks], o[mfq][hf], 0, 0, 0);
    }
    cur ^= 1;
  }

  // epilogue — row-state shuffle for 1/lst (r5 fix)
#pragma unroll
  for (int nfq = 0; nfq < 2; ++nfq) {
    const float rl = 1.f / lst[nfq];
    float rr[4];
#pragma unroll
    for (int r = 0; r < 4; ++r) rr[r] = __shfl(rl, sbase + l4 * 4 + r);
#pragma unroll
    for (int hf = 0; hf < 4; ++hf)
#pragma unroll
      for (int r = 0; r < 4; ++r) {
        const int qrow = qrow0 + nfq * 16 + l4 * 4 + r;
        const int col = h * 64 + hf * 16 + l15;
        Abf[((size_t)b * NIMG + qrow) * DIMG + col] = f2bf(o[nfq][hf][r] * rr[r]);
      }
  }
}

// ---------------------------------------------------------------------------
extern "C" void kernel_launch(void* const* d_in, const int* in_sizes, int n_in,
                              void* d_out, int out_size, void* d_ws, size_t ws_size,
                              hipStream_t stream) {
  const float* img  = (const float*)d_in[0];
  const float* txt  = (const float*)d_in[1];
  const int*   mask = (const int*)d_in[2];
  const float* Wq   = (const float*)d_in[3];
  const float* Wk   = (const float*)d_in[4];
  const float* Wv   = (const float*)d_in[5];
  const float* Wo   = (const float*)d_in[6];
  const float* bo   = (const float*)d_in[7];
  float* out = (float*)d_out;

  char* ws = (char*)d_ws;
  u16* imgBf = (u16*)ws;                        // 33.55 MB; reused as Abf after Q-proj
  u16* Qbf   = (u16*)(ws + 33554432);           // 33.55 MB
  u16* Kbf   = (u16*)(ws + 67108864);           //  4.19 MB
  u16* Vtw   = (u16*)(ws + 71303168);           //  4.19 MB
  u16* WqBf  = (u16*)(ws + 75497472);           //  0.52 MB
  u16* WoBf  = (u16*)(ws + 76021760);           //  0.52 MB  (total 76.5 MB)

  convk<<<2048, 256, 0, stream>>>(img, imgBf, NB * NIMG * DIMG / 8);
  convk<<<128,  256, 0, stream>>>(Wq, WqBf, DIMG * DIMG / 8);
  convk<<<128,  256, 0, stream>>>(Wo, WoBf, DIMG * DIMG / 8);

  // Q = img @ Wq^T  (32768 x 512 x 512), head-split bf16
  gemm_bf<0, NIMG><<<dim3(4, 256), 256, 0, stream>>>(imgBf, WqBf, nullptr, Qbf, DIMG, DIMG);
  // K, V^T = txt @ {Wk,Wv}^T  (4096 x 512 x 768)
  gemm_kv<<<dim3(8, 32), 256, 0, stream>>>(txt, Wk, Wv, Kbf, Vtw);
  // attention -> Abf (overwrites imgBf; img dead after Q-proj)
  attn_k<<<dim3(NB * NH * (NIMG / 128)), 256, 0, stream>>>(Qbf, Kbf, Vtw, mask, imgBf);
  // out = attended @ Wo^T + bo  (32768 x 512 x 512), fp32
  gemm_bf<2, 1><<<dim3(4, 256), 256, 0, stream>>>(imgBf, WoBf, bo, out, DIMG, DIMG);
}